// Round 4
// baseline (252.321 us; speedup 1.0000x reference)
//
#include <hip/hip_runtime.h>

// cost[b,dd,ii,j,c,uv] = (bounds? x[b,c,uv, ii+d*(4-u), j+d*(4-v)] : 0) * mask[b,uv,ii,j]
// d = dd-4, u=uv/9, v=uv%9.  out = cost (b,9,96,96,324) flat, then ctr = x[:,:,40,:,:].
//
// v4 = R3 (XCD-band swizzle) + JB 32->24: LDS 44->33.7 KB so 4 blocks/CU
// (32 waves/CU, the HW cap, vs 24 before). __launch_bounds__(512,8) pins
// VGPR<=64 so 8 waves/SIMD materializes. Phase 1 is exactly one 4x4 tile
// per thread (486 items, no loop). Swizzle stays bijective: 6912 = 8*864.

#define NAA 81
#define H 96
#define W 96
#define NC 4
#define ND 9
#define PLANE 9216          // 96*96
#define NR 324              // rows = c*81+uv
#define JB 24               // j per block
#define OUTROW 31104        // W*NR
#define CTR_OFF 53747712LL  // 2*9*96*96*324
#define XTOT 5971968        // total floats in x

typedef float f32x4 __attribute__((ext_vector_type(4)));
typedef f32x4 __attribute__((aligned(4))) f32x4u;   // 4B-aligned vector load

__global__ __launch_bounds__(512, 8)
void build_cost_kernel(const float* __restrict__ x, const float* __restrict__ mask,
                       float* __restrict__ out) {
    __shared__ __align__(16) float xs[JB * NR];   // xs[jj*NR + row]  (31,104 B)
    __shared__ __align__(16) int   lut[2 * NR];   // per row: {xb_or_-1, (mb<<6)|(s+16)}

    // ---- XCD-band swizzle decode (bijective: 6912 dispatches = 8 XCD * 864) ----
    const int D   = blockIdx.x;      // 0..6911
    const int xcd = D & 7;           // target XCD (HW round-robin over dispatch id)
    const int s_  = D >> 3;          // 0..863: slot within XCD
    const int b   = s_ / 432;        // slowest: batch
    const int w_  = s_ - 432 * b;    // 0..431
    const int dd  = w_ / 48;         // slow: disparity 0..8
    const int r_  = w_ - 48 * dd;
    const int jc  = r_ / 12;         // mid: j-chunk 0..3
    const int iio = r_ - 12 * jc;    // fast: ii within band
    const int ii  = 12 * xcd + iio;  // spatial row
    const int j0  = JB * jc;
    const int d   = dd - 4;
    const int tid = threadIdx.x;

    // ---- phase 0: packed per-row LUT (324 rows) ----
    if (tid < NR) {
        int row = tid;                   // row = c*81 + uv
        int c  = row / 81;
        int uv = row - 81 * c;
        int u  = uv / 9;
        int v  = uv - 9 * u;
        int ri = ii + d * (4 - u);
        int xb = ((b * NC + c) * NAA + uv) * PLANE + ri * W;
        int mb = ((b * NAA + uv) * H + ii) * W;
        int s  = d * (4 - v);
        lut[2 * tid]     = ((unsigned)ri < (unsigned)H) ? xb : -1;
        lut[2 * tid + 1] = (mb << 6) | (s + 16);
    }
    __syncthreads();

    // ---- phase 1: one 4x4 tile per thread. item = (row-quad rq, j-quad j4) ----
    if (tid < NAA * 6) {                 // 486 items
        int rq = tid / 6;                // row quad 0..80
        int j4 = tid - 6 * rq;           // j quad 0..5
        int jb = 4 * j4;
        int4 P0 = *(const int4*)&lut[8 * rq];       // rows 4rq, 4rq+1
        int4 P1 = *(const int4*)&lut[8 * rq + 4];   // rows 4rq+2, 4rq+3

        auto ld = [&](int xb, int B) -> f32x4 {
            int s    = (B & 63) - 16;
            int col0 = j0 + jb + s;
            int a0   = xb + col0;
            int addr = min(max(a0, 0), XTOT - 4);
            f32x4 xv = *(const f32x4u*)(x + addr);
            f32x4 mv = *(const f32x4*)(mask + (B >> 6) + j0 + jb);
            f32x4 r;
            bool rv = (xb >= 0);
            r.x = (rv && (unsigned)(col0 + 0) < (unsigned)W) ? xv.x * mv.x : 0.0f;
            r.y = (rv && (unsigned)(col0 + 1) < (unsigned)W) ? xv.y * mv.y : 0.0f;
            r.z = (rv && (unsigned)(col0 + 2) < (unsigned)W) ? xv.z * mv.z : 0.0f;
            r.w = (rv && (unsigned)(col0 + 3) < (unsigned)W) ? xv.w * mv.w : 0.0f;
            return r;
        };

        f32x4 v0 = ld(P0.x, P0.y);
        f32x4 v1 = ld(P0.z, P0.w);
        f32x4 v2 = ld(P1.x, P1.y);
        f32x4 v3 = ld(P1.z, P1.w);

        // transpose 4x4 in registers; column t -> rows 4rq..4rq+3 at jj=jb+t
        float* base = &xs[4 * rq];
        f32x4 w0 = {v0.x, v1.x, v2.x, v3.x};
        f32x4 w1 = {v0.y, v1.y, v2.y, v3.y};
        f32x4 w2 = {v0.z, v1.z, v2.z, v3.z};
        f32x4 w3 = {v0.w, v1.w, v2.w, v3.w};
        *(f32x4*)(base + (jb + 0) * NR) = w0;
        *(f32x4*)(base + (jb + 1) * NR) = w1;
        *(f32x4*)(base + (jb + 2) * NR) = w2;
        *(f32x4*)(base + (jb + 3) * NR) = w3;
    }
    __syncthreads();

    // ---- phase 2: contiguous, aligned stores in output order ----
    // out offset = obase + 4*idx; LDS addr = 16*idx bytes (purely linear,
    // conflict-free b128 reads). 1944 vec4 stores, 31,104 B span per block.
    const size_t obase = (size_t)((b * ND + dd) * H + ii) * OUTROW + (size_t)j0 * NR;
    for (int idx = tid; idx < JB * NR / 4; idx += 512) {
        f32x4 v = *(const f32x4*)&xs[4 * idx];
        __builtin_nontemporal_store(v, (f32x4*)(out + obase + 4 * (size_t)idx));
    }

    // ---- ctr output: x[b,c,40,ii,:] (done by dd==4, jc==0 blocks) ----
    if (dd == 4 && jc == 0 && tid < 96) {
        int c = tid / 24;
        int q = tid - 24 * c;
        size_t so  = (size_t)((b * NC + c) * NAA + 40) * PLANE + (size_t)ii * W + 4 * q;
        size_t dst = CTR_OFF + (size_t)((b * NC + c) * H + ii) * W + 4 * q;
        f32x4 cv = *(const f32x4*)(x + so);
        __builtin_nontemporal_store(cv, (f32x4*)(out + dst));
    }
}

extern "C" void kernel_launch(void* const* d_in, const int* in_sizes, int n_in,
                              void* d_out, int out_size, void* d_ws, size_t ws_size,
                              hipStream_t stream) {
    const float* x    = (const float*)d_in[0];
    const float* mask = (const float*)d_in[1];
    float* out = (float*)d_out;
    dim3 grid(6912, 1, 1);   // flattened; XCD-band swizzle decoded in-kernel
    build_cost_kernel<<<grid, 512, 0, stream>>>(x, mask, out);
}